// Round 7
// baseline (276.326 us; speedup 1.0000x reference)
//
#include <hip/hip_runtime.h>

#define N_NODES 100000
#define N_EDGES 1600000
#define D 128

#define NB 782                  // coarse buckets: 128 rows each
#define SLOT 2560               // slots per bucket (mean 2046 + 11 sigma slack)
#define CHUNK 6400              // edges per bucket_coarse block
#define NBLK_BUCKET 250         // 250 * 6400 = 1.6M

#define NPHASE 8                // col ranges of 12500 rows = 3.2 MB HWb slice each
#define COLS_PER_PHASE 12500

// workspace layout (bytes)
#define WB_OFF     0u           // 32 KB bf16 W
#define HWB_OFF    65536u       // 25.6 MB bf16 HW
#define BCNT_OFF   25665536u    // 782 ints (pad to 4 KB)
#define EPACK0_OFF 25669632u    // NB*SLOT int2 = 16,015,360 B
// end ~41.7 MB

typedef unsigned int uint;
typedef __attribute__((ext_vector_type(4))) float f32x4;
typedef __attribute__((ext_vector_type(8))) short bf16x8;

__device__ __forceinline__ unsigned short f2bf(float x) {
    uint u = __float_as_uint(x);
    uint r = u + 0x7fffu + ((u >> 16) & 1u);   // round-to-nearest-even
    return (unsigned short)(r >> 16);
}

__device__ __forceinline__ void acc8(float acc[8], uint4 q, float v) {
    acc[0] = fmaf(v, __uint_as_float(q.x << 16),         acc[0]);
    acc[1] = fmaf(v, __uint_as_float(q.x & 0xffff0000u), acc[1]);
    acc[2] = fmaf(v, __uint_as_float(q.y << 16),         acc[2]);
    acc[3] = fmaf(v, __uint_as_float(q.y & 0xffff0000u), acc[3]);
    acc[4] = fmaf(v, __uint_as_float(q.z << 16),         acc[4]);
    acc[5] = fmaf(v, __uint_as_float(q.z & 0xffff0000u), acc[5]);
    acc[6] = fmaf(v, __uint_as_float(q.w << 16),         acc[6]);
    acc[7] = fmaf(v, __uint_as_float(q.w & 0xffff0000u), acc[7]);
}

// ---------------------------------------------------------------------------
__global__ void k_cast_w(const float* __restrict__ W, unsigned short* __restrict__ Wb) {
    int i = blockIdx.x * blockDim.x + threadIdx.x;   // 0..16383
    Wb[i] = f2bf(W[i]);
}

// ---------------------------------------------------------------------------
// HWb = bf16( H @ W^T ) via mfma_f32_16x16x32_bf16. One wave per 16 rows.
__global__ __launch_bounds__(256) void k_gemm_mfma(const float* __restrict__ H,
                                                   const unsigned short* __restrict__ Wb,
                                                   unsigned short* __restrict__ HWb) {
    const int wave = threadIdx.x >> 6;
    const int lane = threadIdx.x & 63;
    const int rowtile = blockIdx.x * 4 + wave;       // 0..6249
    if (rowtile >= N_NODES / 16) return;
    const int rowbase = rowtile * 16;
    const int m    = lane & 15;
    const int quad = lane >> 4;

    f32x4 acc[8];
    #pragma unroll
    for (int nt = 0; nt < 8; ++nt) acc[nt] = (f32x4){0.f, 0.f, 0.f, 0.f};

    const float* hrow = H + (size_t)(rowbase + m) * D;

    #pragma unroll
    for (int ks = 0; ks < 4; ++ks) {
        const int k0 = ks * 32 + quad * 8;
        float4 a0 = *(const float4*)(hrow + k0);
        float4 a1 = *(const float4*)(hrow + k0 + 4);
        bf16x8 afr;
        afr[0] = (short)f2bf(a0.x); afr[1] = (short)f2bf(a0.y);
        afr[2] = (short)f2bf(a0.z); afr[3] = (short)f2bf(a0.w);
        afr[4] = (short)f2bf(a1.x); afr[5] = (short)f2bf(a1.y);
        afr[6] = (short)f2bf(a1.z); afr[7] = (short)f2bf(a1.w);
        #pragma unroll
        for (int nt = 0; nt < 8; ++nt) {
            bf16x8 bfr = *(const bf16x8*)(Wb + (size_t)(nt * 16 + m) * D + k0);
            acc[nt] = __builtin_amdgcn_mfma_f32_16x16x32_bf16(afr, bfr, acc[nt], 0, 0, 0);
        }
    }

    #pragma unroll
    for (int nt = 0; nt < 8; ++nt) {
        #pragma unroll
        for (int r = 0; r < 4; ++r) {
            int orow = rowbase + quad * 4 + r;
            HWb[(size_t)orow * D + nt * 16 + m] = f2bf(acc[nt][r]);
        }
    }
}

// ---------------------------------------------------------------------------
// Pass 1: coarse-bucket edges by row>>7. Block-local LDS count, one global
// atomic span reservation per (block,bucket), dense-in-time placement.
// epack0 entry: x = (local_row<<17) | col, y = val bits.
__global__ __launch_bounds__(256) void k_bucket_coarse(const int* __restrict__ rows,
                                                       const int* __restrict__ cols,
                                                       const float* __restrict__ vals,
                                                       int* __restrict__ bcnt,
                                                       int2* __restrict__ epack0) {
    __shared__ int srows[CHUNK];        // 25.6 KB
    __shared__ int hist[NB];            // 3.1 KB
    __shared__ int cur[NB];             // 3.1 KB
    const int tid = threadIdx.x;
    const int e0  = blockIdx.x * CHUNK;

    for (int b = tid; b < NB; b += 256) hist[b] = 0;
    __syncthreads();

    for (int i = tid; i < CHUNK; i += 256) {
        int r = rows[e0 + i];
        srows[i] = r;
        atomicAdd(&hist[r >> 7], 1);
    }
    __syncthreads();

    for (int b = tid; b < NB; b += 256) {
        int c = hist[b];
        int base = (c > 0) ? atomicAdd(&bcnt[b], c) : 0;
        cur[b] = b * SLOT + base;
    }
    __syncthreads();

    for (int i = tid; i < CHUNK; i += 256) {
        int r = srows[i];
        int b = r >> 7;
        int p = atomicAdd(&cur[b], 1);
        epack0[p] = make_int2(((r & 127) << 17) | cols[e0 + i],
                              __float_as_int(vals[e0 + i]));
    }
}

// ---------------------------------------------------------------------------
// Pass 2 (fused sort + phased SpMM + ReLU): one block per bucket.
// LDS counting-sort by key = (local_row<<3) | col_range (1024 bins), then
// gather with PHASE (col_range) OUTERMOST: at any instant the whole chip
// touches ~one 3.2 MB HWb slice -> per-XCD L2 holds it -> misses become
// streaming per-phase fills, hits are L2-local. Row accumulators (8 rows x
// 8 floats) persist in VGPRs across phases; each out row written once.
__global__ __launch_bounds__(256) void k_spmm_fused(const int* __restrict__ bcnt,
                                                    const int2* __restrict__ epack0,
                                                    const unsigned short* __restrict__ HWb,
                                                    float* __restrict__ out) {
    __shared__ int   scol[SLOT];        // 10.24 KB
    __shared__ float sval[SLOT];        // 10.24 KB
    __shared__ int hist[1024];          // 4 KB  (becomes seg-start after scan)
    __shared__ int cur[1024];           // 4 KB  (becomes seg-end after placement)
    __shared__ int tsum[256];           // 1 KB
    const int tid  = threadIdx.x;
    const int b    = blockIdx.x;
    const int base = b * SLOT;
    const int n_e  = bcnt[b];

    for (int i = tid; i < 1024; i += 256) hist[i] = 0;
    __syncthreads();

    for (int i = tid; i < n_e; i += 256) {
        int2 e  = epack0[base + i];
        int col = e.x & 0x1FFFF;
        int key = ((e.x >> 17) << 3) | (col / COLS_PER_PHASE);
        atomicAdd(&hist[key], 1);
    }
    __syncthreads();

    // exclusive scan over 1024 bins: 4 serial per thread + 256-scan + add-back
    int run = 0;
    #pragma unroll
    for (int k = 0; k < 4; ++k) {
        int t2 = hist[tid * 4 + k];
        hist[tid * 4 + k] = run;
        run += t2;
    }
    tsum[tid] = run;
    __syncthreads();
    int myv = run;
    #pragma unroll
    for (int off = 1; off < 256; off <<= 1) {
        int t2 = (tid >= off) ? tsum[tid - off] : 0;
        __syncthreads();
        tsum[tid] += t2;
        __syncthreads();
    }
    int tbase = tsum[tid] - myv;        // exclusive block base for this thread's 4 bins
    #pragma unroll
    for (int k = 0; k < 4; ++k) hist[tid * 4 + k] += tbase;
    __syncthreads();
    for (int i = tid; i < 1024; i += 256) cur[i] = hist[i];
    __syncthreads();

    // place sorted (col,val) into LDS (re-read epack0: L2-warm)
    for (int i = tid; i < n_e; i += 256) {
        int2 e  = epack0[base + i];
        int col = e.x & 0x1FFFF;
        int key = ((e.x >> 17) << 3) | (col / COLS_PER_PHASE);
        int p   = atomicAdd(&cur[key], 1);
        scol[p] = col;
        sval[p] = __int_as_float(e.y);
    }
    __syncthreads();

    // phased gather: group (tid>>4) owns rows group*8 .. group*8+7
    const int lane  = tid & 15;
    const int group = tid >> 4;

    float acc[8][8];
    #pragma unroll
    for (int rr = 0; rr < 8; ++rr)
        #pragma unroll
        for (int c = 0; c < 8; ++c) acc[rr][c] = 0.f;

    for (int p = 0; p < NPHASE; ++p) {
        #pragma unroll
        for (int rr = 0; rr < 8; ++rr) {
            const int key = ((group * 8 + rr) << 3) | p;
            int j  = hist[key];
            int e_ = cur[key];
            for (; j + 1 < e_; j += 2) {
                int   c0 = scol[j],     c1 = scol[j + 1];
                float v0 = sval[j],     v1 = sval[j + 1];
                uint4 q0 = ((const uint4*)(HWb + (size_t)c0 * D))[lane];
                uint4 q1 = ((const uint4*)(HWb + (size_t)c1 * D))[lane];
                acc8(acc[rr], q0, v0);
                acc8(acc[rr], q1, v1);
            }
            if (j < e_) {
                int   c = scol[j];
                float v = sval[j];
                uint4 q = ((const uint4*)(HWb + (size_t)c * D))[lane];
                acc8(acc[rr], q, v);
            }
        }
    }

    #pragma unroll
    for (int rr = 0; rr < 8; ++rr) {
        const int row = b * 128 + group * 8 + rr;
        if (row < N_NODES) {
            float4 o0 = make_float4(fmaxf(acc[rr][0], 0.f), fmaxf(acc[rr][1], 0.f),
                                    fmaxf(acc[rr][2], 0.f), fmaxf(acc[rr][3], 0.f));
            float4 o1 = make_float4(fmaxf(acc[rr][4], 0.f), fmaxf(acc[rr][5], 0.f),
                                    fmaxf(acc[rr][6], 0.f), fmaxf(acc[rr][7], 0.f));
            ((float4*)out)[row * 32 + lane * 2]     = o0;
            ((float4*)out)[row * 32 + lane * 2 + 1] = o1;
        }
    }
}

// ---------------------------------------------------------------------------
extern "C" void kernel_launch(void* const* d_in, const int* in_sizes, int n_in,
                              void* d_out, int out_size, void* d_ws, size_t ws_size,
                              hipStream_t stream) {
    const float* H    = (const float*)d_in[0];
    const float* vals = (const float*)d_in[1];
    const float* W    = (const float*)d_in[2];
    const int*   rows = (const int*)d_in[3];
    const int*   cols = (const int*)d_in[4];
    float* out = (float*)d_out;

    char* ws = (char*)d_ws;
    unsigned short* Wb     = (unsigned short*)(ws + WB_OFF);
    unsigned short* HWb    = (unsigned short*)(ws + HWB_OFF);
    int*            bcnt   = (int*)(ws + BCNT_OFF);
    int2*           epack0 = (int2*)(ws + EPACK0_OFF);

    // dense path: HWb = bf16(H @ W^T), MFMA
    k_cast_w<<<64, 256, 0, stream>>>(W, Wb);
    k_gemm_mfma<<<(N_NODES / 16 + 3) / 4, 256, 0, stream>>>(H, Wb, HWb);

    // coarse bucket, then fused sort + phased SpMM + ReLU
    hipMemsetAsync(bcnt, 0, NB * sizeof(int), stream);
    k_bucket_coarse<<<NBLK_BUCKET, 256, 0, stream>>>(rows, cols, vals, bcnt, epack0);
    k_spmm_fused<<<NB, 256, 0, stream>>>(bcnt, epack0, HWb, out);
}